// Round 2
// baseline (1734.073 us; speedup 1.0000x reference)
//
#include <hip/hip_runtime.h>
#include <hip/hip_bf16.h>

typedef __attribute__((ext_vector_type(8))) short bf16x8;   // 8 bf16 = 4 VGPRs (MFMA A/B frag)
typedef __attribute__((ext_vector_type(4))) float f32x4;    // MFMA C/D frag
typedef unsigned short ushort_t;

#define NN   100000
#define NE   3200000
#define IND  512
#define HIDD 256
#define OUTD 64

// bf16 helpers (RTNE, manual bit math — no NaN inputs in this problem)
__device__ __forceinline__ ushort_t f2bf(float a) {
    unsigned u = __float_as_uint(a);
    unsigned r = (u + 0x7FFFu + ((u >> 16) & 1u)) >> 16;
    return (ushort_t)r;
}
__device__ __forceinline__ float bf2f(ushort_t b) {
    return __uint_as_float(((unsigned)b) << 16);
}

union U8 { ushort_t us[8]; uint4 v; };

// ------------------------------------------------- weight transpose + hi/lo split
// in: fp32 [R,C] row-major -> out hi/lo: bf16 [C,R] (i.e. B^T with contiguous K)
__global__ void splitw_k(const float* __restrict__ in, ushort_t* __restrict__ thi,
                         ushort_t* __restrict__ tlo, int R, int C) {
    int i = blockIdx.x * 256 + threadIdx.x;
    if (i < R * C) {
        int r = i / C, c = i % C;
        float a = in[i];
        ushort_t h = f2bf(a);
        thi[(size_t)c * R + r] = h;
        tlo[(size_t)c * R + r] = f2bf(a - bf2f(h));
    }
}

// ------------------------------------------------- split-bf16 GEMM (fp32-accurate)
// C[M,N] = A[M,K] @ B[K,N]; A fp32 (split on the fly), Bt pre-split bf16 [N,K].
// BM=128, BN=64, BK=32; 256 threads = 4 waves; wave tile 32x64 as 2x4 mfma tiles.
__global__ __launch_bounds__(256) void gemm_split_k(
    const float* __restrict__ A, const ushort_t* __restrict__ BtHi,
    const ushort_t* __restrict__ BtLo, float* __restrict__ C,
    int M, int N, int K)
{
    // row stride 40 elems = 80 B = 20 banks -> only 2-way LDS aliasing (free)
    __shared__ __align__(16) ushort_t sAh[128][40];
    __shared__ __align__(16) ushort_t sAl[128][40];
    __shared__ __align__(16) ushort_t sBh[64][40];
    __shared__ __align__(16) ushort_t sBl[64][40];

    const int tid  = threadIdx.x;
    const int wave = tid >> 6;
    const int lane = tid & 63;
    const int quad = lane >> 4;
    const int l15  = lane & 15;
    const int m0   = blockIdx.x * 128;
    const int n0   = blockIdx.y * 64;

    f32x4 acc[2][4] = {};

    const int sr = tid >> 2;          // 0..63 staging row
    const int sc = (tid & 3) * 8;     // 0,8,16,24 staging col (k)

    for (int k0 = 0; k0 < K; k0 += 32) {
        // stage A: 128 rows x 32 k, fp32 -> hi/lo bf16, two sweeps of 64 rows
        #pragma unroll
        for (int it = 0; it < 2; ++it) {
            int rr = sr + it * 64;
            int gr = m0 + rr;
            float4 v0 = make_float4(0.f, 0.f, 0.f, 0.f);
            float4 v1 = v0;
            if (gr < M) {
                const float* p = A + (size_t)gr * K + k0 + sc;
                v0 = *(const float4*)p;
                v1 = *(const float4*)(p + 4);
            }
            float vv[8] = {v0.x, v0.y, v0.z, v0.w, v1.x, v1.y, v1.z, v1.w};
            U8 H, L;
            #pragma unroll
            for (int j = 0; j < 8; ++j) {
                ushort_t h = f2bf(vv[j]);
                H.us[j] = h;
                L.us[j] = f2bf(vv[j] - bf2f(h));
            }
            *(uint4*)&sAh[rr][sc] = H.v;
            *(uint4*)&sAl[rr][sc] = L.v;
        }
        // stage Bt (pre-split): 64 rows x 32 k
        *(uint4*)&sBh[sr][sc] = *(const uint4*)(BtHi + (size_t)(n0 + sr) * K + k0 + sc);
        *(uint4*)&sBl[sr][sc] = *(const uint4*)(BtLo + (size_t)(n0 + sr) * K + k0 + sc);
        __syncthreads();

        bf16x8 aH[2], aL[2], bH[4], bL[4];
        #pragma unroll
        for (int ms = 0; ms < 2; ++ms) {
            aH[ms] = *(const bf16x8*)&sAh[wave * 32 + ms * 16 + l15][quad * 8];
            aL[ms] = *(const bf16x8*)&sAl[wave * 32 + ms * 16 + l15][quad * 8];
        }
        #pragma unroll
        for (int ns = 0; ns < 4; ++ns) {
            bH[ns] = *(const bf16x8*)&sBh[ns * 16 + l15][quad * 8];
            bL[ns] = *(const bf16x8*)&sBl[ns * 16 + l15][quad * 8];
        }

        #pragma unroll
        for (int ms = 0; ms < 2; ++ms)
            #pragma unroll
            for (int ns = 0; ns < 4; ++ns) {
                acc[ms][ns] = __builtin_amdgcn_mfma_f32_16x16x32_bf16(
                    aH[ms], bH[ns], acc[ms][ns], 0, 0, 0);
                acc[ms][ns] = __builtin_amdgcn_mfma_f32_16x16x32_bf16(
                    aL[ms], bH[ns], acc[ms][ns], 0, 0, 0);
                acc[ms][ns] = __builtin_amdgcn_mfma_f32_16x16x32_bf16(
                    aH[ms], bL[ns], acc[ms][ns], 0, 0, 0);
            }
        __syncthreads();
    }

    // epilogue: C/D layout col=lane&15, row=quad*4+reg
    #pragma unroll
    for (int ms = 0; ms < 2; ++ms) {
        int rowbase = m0 + wave * 32 + ms * 16 + quad * 4;
        #pragma unroll
        for (int ns = 0; ns < 4; ++ns) {
            int col = n0 + ns * 16 + l15;
            #pragma unroll
            for (int r = 0; r < 4; ++r) {
                int row = rowbase + r;
                if (row < M) C[(size_t)row * N + col] = acc[ms][ns][r];
            }
        }
    }
}

// ---------------------------------------------------------------- CSR build
__global__ void hist_k(const int* __restrict__ dst, int* __restrict__ cnt) {
    int i = blockIdx.x * 256 + threadIdx.x;
    if (i < NE) atomicAdd(&cnt[dst[i]], 1);
}

__global__ __launch_bounds__(256) void scan1_k(const int* __restrict__ in,
                                               int* __restrict__ excl,
                                               int* __restrict__ part, int n) {
    __shared__ int s[256];
    int t = threadIdx.x;
    int i = blockIdx.x * 256 + t;
    int v = (i < n) ? in[i] : 0;
    s[t] = v;
    #pragma unroll
    for (int off = 1; off < 256; off <<= 1) {
        __syncthreads();
        int add = (t >= off) ? s[t - off] : 0;
        __syncthreads();
        s[t] += add;
    }
    __syncthreads();
    if (i < n) excl[i] = s[t] - v;
    if (t == 255) part[blockIdx.x] = s[255];
}

__global__ __launch_bounds__(512) void scan2_k(int* __restrict__ part, int nb) {
    __shared__ int s[512];
    int t = threadIdx.x;
    int v = (t < nb) ? part[t] : 0;
    s[t] = v;
    for (int off = 1; off < 512; off <<= 1) {
        __syncthreads();
        int add = (t >= off) ? s[t - off] : 0;
        __syncthreads();
        s[t] += add;
    }
    __syncthreads();
    if (t < nb) part[t] = s[t] - v;
}

__global__ void scan3_k(int* __restrict__ excl, const int* __restrict__ part,
                        int n, int total) {
    int i = blockIdx.x * 256 + threadIdx.x;
    if (i < n) excl[i] += part[blockIdx.x];
    if (i == 0) excl[n] = total;
}

__global__ void fill_k(const int* __restrict__ src, const int* __restrict__ dst,
                       const float* __restrict__ w, int* __restrict__ cursor,
                       int2* __restrict__ esw) {
    int i = blockIdx.x * 256 + threadIdx.x;
    if (i < NE) {
        int d = dst[i];
        int p = atomicAdd(&cursor[d], 1);
        esw[p] = make_int2(src[i], __float_as_int(w[i]));
    }
}

// ---------------------------------------------------------------- SpMM layer 1 (+ReLU)
// one block (256 threads) per dst node; thread = feature column; fp32 throughout
__global__ __launch_bounds__(256) void spmm_relu_k(
    const int* __restrict__ rowptr, const int2* __restrict__ esw,
    const float* __restrict__ X, float* __restrict__ Y)
{
    int node = blockIdx.x;
    int f = threadIdx.x;
    int beg = rowptr[node], end = rowptr[node + 1];
    float acc = 0.f;
    for (int e = beg; e < end; ++e) {
        int2 sw = esw[e];
        acc += __int_as_float(sw.y) * X[(size_t)sw.x * HIDD + f];
    }
    Y[(size_t)node * HIDD + f] = fmaxf(acc, 0.f);
}

// ---------------------------------------------------------------- SpMM layer 2 + softmax
// one wave per dst node; lane = feature column (64)
__global__ __launch_bounds__(256) void spmm_softmax_k(
    const int* __restrict__ rowptr, const int2* __restrict__ esw,
    const float* __restrict__ X, float* __restrict__ out)
{
    int node = blockIdx.x * 4 + (threadIdx.x >> 6);
    int lane = threadIdx.x & 63;
    int beg = rowptr[node], end = rowptr[node + 1];
    float acc = 0.f;
    for (int e = beg; e < end; ++e) {
        int2 sw = esw[e];
        acc += __int_as_float(sw.y) * X[(size_t)sw.x * OUTD + lane];
    }
    // softmax over 64 lanes (degree-0 rows -> uniform 1/64, matches reference)
    float mx = acc;
    #pragma unroll
    for (int off = 32; off > 0; off >>= 1) mx = fmaxf(mx, __shfl_xor(mx, off));
    float ex = __expf(acc - mx);
    float sm = ex;
    #pragma unroll
    for (int off = 32; off > 0; off >>= 1) sm += __shfl_xor(sm, off);
    out[(size_t)node * OUTD + lane] = ex / sm;
}

// ---------------------------------------------------------------- launch
extern "C" void kernel_launch(void* const* d_in, const int* in_sizes, int n_in,
                              void* d_out, int out_size, void* d_ws, size_t ws_size,
                              hipStream_t stream) {
    const float* x  = (const float*)d_in[0];
    const int*   ei = (const int*)d_in[1];
    const float* ew = (const float*)d_in[2];
    const float* W1 = (const float*)d_in[3];
    const float* W2 = (const float*)d_in[4];
    float* out = (float*)d_out;
    const int* src = ei;        // edge_index row 0
    const int* dst = ei + NE;   // edge_index row 1

    char* ws = (char*)d_ws;
    size_t o = 0;
    auto take = [&](size_t bytes) -> void* {
        void* p = (void*)(ws + o);
        o += (bytes + 255) & ~(size_t)255;
        return p;
    };
    float*    S1     = (float*   )take((size_t)NN * HIDD * 4);   // 102.4 MB (reused for S2)
    float*    h      = (float*   )take((size_t)NN * HIDD * 4);   // 102.4 MB
    ushort_t* W1tHi  = (ushort_t*)take((size_t)IND * HIDD * 2);
    ushort_t* W1tLo  = (ushort_t*)take((size_t)IND * HIDD * 2);
    ushort_t* W2tHi  = (ushort_t*)take((size_t)HIDD * OUTD * 2);
    ushort_t* W2tLo  = (ushort_t*)take((size_t)HIDD * OUTD * 2);
    int*      rowptr = (int*     )take((size_t)(NN + 1) * 4);
    int*      cnt    = (int*     )take((size_t)NN * 4);
    int*      cursor = (int*     )take((size_t)NN * 4);
    int*      part   = (int*     )take(512 * 4);
    int2*     esw    = (int2*    )take((size_t)NE * 8);          // 25.6 MB
    float*    S2     = S1;                                       // alias: S1 dead after spmm1
    (void)in_sizes; (void)n_in; (void)out_size; (void)ws_size;

    const int NB = (NN + 255) / 256;          // 391
    const int MB = (NN + 127) / 128;          // 782

    hipMemsetAsync(cnt, 0, (size_t)NN * 4, stream);
    splitw_k<<<(IND * HIDD + 255) / 256, 256, 0, stream>>>(W1, W1tHi, W1tLo, IND, HIDD);
    splitw_k<<<(HIDD * OUTD + 255) / 256, 256, 0, stream>>>(W2, W2tHi, W2tLo, HIDD, OUTD);

    hist_k<<<(NE + 255) / 256, 256, 0, stream>>>(dst, cnt);
    scan1_k<<<NB, 256, 0, stream>>>(cnt, rowptr, part, NN);
    scan2_k<<<1, 512, 0, stream>>>(part, NB);
    scan3_k<<<NB, 256, 0, stream>>>(rowptr, part, NN, NE);
    hipMemcpyAsync(cursor, rowptr, (size_t)NN * 4, hipMemcpyDeviceToDevice, stream);
    fill_k<<<(NE + 255) / 256, 256, 0, stream>>>(src, dst, ew, cursor, esw);

    // layer 1: S1 = x @ W1 (fp32-accurate split GEMM), h = relu(A_sp @ S1)
    gemm_split_k<<<dim3(MB, HIDD / 64), 256, 0, stream>>>(x, W1tHi, W1tLo, S1, NN, HIDD, IND);
    spmm_relu_k<<<NN, 256, 0, stream>>>(rowptr, esw, S1, h);
    // layer 2: S2 = h @ W2, out = softmax(A_sp @ S2)
    gemm_split_k<<<dim3(MB, OUTD / 64), 256, 0, stream>>>(h, W2tHi, W2tLo, S2, NN, OUTD, HIDD);
    spmm_softmax_k<<<NN / 4, 256, 0, stream>>>(rowptr, esw, S2, out);
}

// Round 4
// 1368.765 us; speedup vs baseline: 1.2669x; 1.2669x over previous
//
#include <hip/hip_runtime.h>
#include <hip/hip_bf16.h>

typedef __attribute__((ext_vector_type(8))) short bf16x8;   // 8 bf16 = 4 VGPRs (MFMA A/B frag)
typedef __attribute__((ext_vector_type(4))) float f32x4;    // MFMA C/D frag
typedef unsigned short ushort_t;

#define NN   100000
#define NE   3200000
#define IND  512
#define HIDD 256
#define OUTD 64

// bf16 helpers (RTNE, manual bit math — no NaN inputs in this problem)
__device__ __forceinline__ ushort_t f2bf(float a) {
    unsigned u = __float_as_uint(a);
    unsigned r = (u + 0x7FFFu + ((u >> 16) & 1u)) >> 16;
    return (ushort_t)r;
}
__device__ __forceinline__ float bf2f(ushort_t b) {
    return __uint_as_float(((unsigned)b) << 16);
}

union U8 { ushort_t us[8]; uint4 v; };

// ------------------------------------------------- weight transpose + hi/lo split
// in: fp32 [R,C] row-major -> out hi/lo: bf16 [C,R] (i.e. B^T with contiguous K)
__global__ void splitw_k(const float* __restrict__ in, ushort_t* __restrict__ thi,
                         ushort_t* __restrict__ tlo, int R, int C) {
    int i = blockIdx.x * 256 + threadIdx.x;
    if (i < R * C) {
        int r = i / C, c = i % C;
        float a = in[i];
        ushort_t h = f2bf(a);
        thi[(size_t)c * R + r] = h;
        tlo[(size_t)c * R + r] = f2bf(a - bf2f(h));
    }
}

// ------------------------------------------------- split-bf16 GEMM (fp32-accurate)
// C[M,N] = A[M,K] @ B[K,N]; A fp32 (split on the fly), Bt pre-split bf16 [N,K].
// BM=128, BN=64, BK=32; 256 threads = 4 waves; wave tile 32x64 as 2x4 mfma tiles.
__global__ __launch_bounds__(256) void gemm_split_k(
    const float* __restrict__ A, const ushort_t* __restrict__ BtHi,
    const ushort_t* __restrict__ BtLo, float* __restrict__ C,
    int M, int N, int K)
{
    // row stride 40 elems = 80 B = 20 banks -> only 2-way LDS aliasing (free)
    __shared__ __align__(16) ushort_t sAh[128][40];
    __shared__ __align__(16) ushort_t sAl[128][40];
    __shared__ __align__(16) ushort_t sBh[64][40];
    __shared__ __align__(16) ushort_t sBl[64][40];

    const int tid  = threadIdx.x;
    const int wave = tid >> 6;
    const int lane = tid & 63;
    const int quad = lane >> 4;
    const int l15  = lane & 15;
    const int m0   = blockIdx.x * 128;
    const int n0   = blockIdx.y * 64;

    f32x4 acc[2][4] = {};

    const int sr = tid >> 2;          // 0..63 staging row
    const int sc = (tid & 3) * 8;     // 0,8,16,24 staging col (k)

    for (int k0 = 0; k0 < K; k0 += 32) {
        // stage A: 128 rows x 32 k, fp32 -> hi/lo bf16, two sweeps of 64 rows
        #pragma unroll
        for (int it = 0; it < 2; ++it) {
            int rr = sr + it * 64;
            int gr = m0 + rr;
            float4 v0 = make_float4(0.f, 0.f, 0.f, 0.f);
            float4 v1 = v0;
            if (gr < M) {
                const float* p = A + (size_t)gr * K + k0 + sc;
                v0 = *(const float4*)p;
                v1 = *(const float4*)(p + 4);
            }
            float vv[8] = {v0.x, v0.y, v0.z, v0.w, v1.x, v1.y, v1.z, v1.w};
            U8 H, L;
            #pragma unroll
            for (int j = 0; j < 8; ++j) {
                ushort_t h = f2bf(vv[j]);
                H.us[j] = h;
                L.us[j] = f2bf(vv[j] - bf2f(h));
            }
            *(uint4*)&sAh[rr][sc] = H.v;
            *(uint4*)&sAl[rr][sc] = L.v;
        }
        // stage Bt (pre-split): 64 rows x 32 k
        *(uint4*)&sBh[sr][sc] = *(const uint4*)(BtHi + (size_t)(n0 + sr) * K + k0 + sc);
        *(uint4*)&sBl[sr][sc] = *(const uint4*)(BtLo + (size_t)(n0 + sr) * K + k0 + sc);
        __syncthreads();

        bf16x8 aH[2], aL[2], bH[4], bL[4];
        #pragma unroll
        for (int ms = 0; ms < 2; ++ms) {
            aH[ms] = *(const bf16x8*)&sAh[wave * 32 + ms * 16 + l15][quad * 8];
            aL[ms] = *(const bf16x8*)&sAl[wave * 32 + ms * 16 + l15][quad * 8];
        }
        #pragma unroll
        for (int ns = 0; ns < 4; ++ns) {
            bH[ns] = *(const bf16x8*)&sBh[ns * 16 + l15][quad * 8];
            bL[ns] = *(const bf16x8*)&sBl[ns * 16 + l15][quad * 8];
        }

        #pragma unroll
        for (int ms = 0; ms < 2; ++ms)
            #pragma unroll
            for (int ns = 0; ns < 4; ++ns) {
                acc[ms][ns] = __builtin_amdgcn_mfma_f32_16x16x32_bf16(
                    aH[ms], bH[ns], acc[ms][ns], 0, 0, 0);
                acc[ms][ns] = __builtin_amdgcn_mfma_f32_16x16x32_bf16(
                    aL[ms], bH[ns], acc[ms][ns], 0, 0, 0);
                acc[ms][ns] = __builtin_amdgcn_mfma_f32_16x16x32_bf16(
                    aH[ms], bL[ns], acc[ms][ns], 0, 0, 0);
            }
        __syncthreads();
    }

    // epilogue: C/D layout col=lane&15, row=quad*4+reg
    #pragma unroll
    for (int ms = 0; ms < 2; ++ms) {
        int rowbase = m0 + wave * 32 + ms * 16 + quad * 4;
        #pragma unroll
        for (int ns = 0; ns < 4; ++ns) {
            int col = n0 + ns * 16 + l15;
            #pragma unroll
            for (int r = 0; r < 4; ++r) {
                int row = rowbase + r;
                if (row < M) C[(size_t)row * N + col] = acc[ms][ns][r];
            }
        }
    }
}

// ---------------------------------------------------------------- CSR build
__global__ void hist_k(const int* __restrict__ dst, int* __restrict__ cnt) {
    int i = blockIdx.x * 256 + threadIdx.x;
    if (i < NE) atomicAdd(&cnt[dst[i]], 1);
}

__global__ __launch_bounds__(256) void scan1_k(const int* __restrict__ in,
                                               int* __restrict__ excl,
                                               int* __restrict__ part, int n) {
    __shared__ int s[256];
    int t = threadIdx.x;
    int i = blockIdx.x * 256 + t;
    int v = (i < n) ? in[i] : 0;
    s[t] = v;
    #pragma unroll
    for (int off = 1; off < 256; off <<= 1) {
        __syncthreads();
        int add = (t >= off) ? s[t - off] : 0;
        __syncthreads();
        s[t] += add;
    }
    __syncthreads();
    if (i < n) excl[i] = s[t] - v;
    if (t == 255) part[blockIdx.x] = s[255];
}

__global__ __launch_bounds__(512) void scan2_k(int* __restrict__ part, int nb) {
    __shared__ int s[512];
    int t = threadIdx.x;
    int v = (t < nb) ? part[t] : 0;
    s[t] = v;
    for (int off = 1; off < 512; off <<= 1) {
        __syncthreads();
        int add = (t >= off) ? s[t - off] : 0;
        __syncthreads();
        s[t] += add;
    }
    __syncthreads();
    if (t < nb) part[t] = s[t] - v;
}

__global__ void scan3_k(int* __restrict__ excl, const int* __restrict__ part,
                        int n, int total) {
    int i = blockIdx.x * 256 + threadIdx.x;
    if (i < n) excl[i] += part[blockIdx.x];
    if (i == 0) excl[n] = total;
}

__global__ void fill_k(const int* __restrict__ src, const int* __restrict__ dst,
                       const float* __restrict__ w, int* __restrict__ cursor,
                       int2* __restrict__ esw) {
    int i = blockIdx.x * 256 + threadIdx.x;
    if (i < NE) {
        int d = dst[i];
        int p = atomicAdd(&cursor[d], 1);
        esw[p] = make_int2(src[i], __float_as_int(w[i]));
    }
}

// ---------------------------------------------------------------- SpMM layer 1 (+ReLU)
// one WAVE per dst node; lane covers 4 features (float4). Same uniform esw[e]
// broadcast load and same sequential edge order as the R2-verified kernel;
// unroll 4 batches independent esw->X chains for latency overlap.
__global__ __launch_bounds__(256) void spmm_relu_k(
    const int* __restrict__ rowptr, const int2* __restrict__ esw,
    const float* __restrict__ X, float* __restrict__ Y)
{
    const int wave = threadIdx.x >> 6;
    const int lane = threadIdx.x & 63;
    const int node = blockIdx.x * 4 + wave;
    const int beg = rowptr[node], end = rowptr[node + 1];
    f32x4 acc = {0.f, 0.f, 0.f, 0.f};
    const float* Xl = X + lane * 4;
    #pragma unroll 4
    for (int e = beg; e < end; ++e) {
        int2 sw = esw[e];
        float w = __int_as_float(sw.y);
        f32x4 v = *(const f32x4*)(Xl + (size_t)sw.x * HIDD);
        acc += v * w;
    }
    f32x4 r;
    r.x = fmaxf(acc.x, 0.f);
    r.y = fmaxf(acc.y, 0.f);
    r.z = fmaxf(acc.z, 0.f);
    r.w = fmaxf(acc.w, 0.f);
    *(f32x4*)(Y + (size_t)node * HIDD + lane * 4) = r;
}

// ---------------------------------------------------------------- SpMM layer 2 + softmax
// one wave per dst node; lane = feature column (64). Verbatim R2 logic + unroll.
__global__ __launch_bounds__(256) void spmm_softmax_k(
    const int* __restrict__ rowptr, const int2* __restrict__ esw,
    const float* __restrict__ X, float* __restrict__ out)
{
    int node = blockIdx.x * 4 + (threadIdx.x >> 6);
    int lane = threadIdx.x & 63;
    int beg = rowptr[node], end = rowptr[node + 1];
    float acc = 0.f;
    #pragma unroll 4
    for (int e = beg; e < end; ++e) {
        int2 sw = esw[e];
        acc += __int_as_float(sw.y) * X[(size_t)sw.x * OUTD + lane];
    }
    // softmax over 64 lanes (degree-0 rows -> uniform 1/64, matches reference)
    float mx = acc;
    #pragma unroll
    for (int off = 32; off > 0; off >>= 1) mx = fmaxf(mx, __shfl_xor(mx, off));
    float ex = __expf(acc - mx);
    float sm = ex;
    #pragma unroll
    for (int off = 32; off > 0; off >>= 1) sm += __shfl_xor(sm, off);
    out[(size_t)node * OUTD + lane] = ex / sm;
}

// ---------------------------------------------------------------- launch
extern "C" void kernel_launch(void* const* d_in, const int* in_sizes, int n_in,
                              void* d_out, int out_size, void* d_ws, size_t ws_size,
                              hipStream_t stream) {
    const float* x  = (const float*)d_in[0];
    const int*   ei = (const int*)d_in[1];
    const float* ew = (const float*)d_in[2];
    const float* W1 = (const float*)d_in[3];
    const float* W2 = (const float*)d_in[4];
    float* out = (float*)d_out;
    const int* src = ei;        // edge_index row 0
    const int* dst = ei + NE;   // edge_index row 1

    char* ws = (char*)d_ws;
    size_t o = 0;
    auto take = [&](size_t bytes) -> void* {
        void* p = (void*)(ws + o);
        o += (bytes + 255) & ~(size_t)255;
        return p;
    };
    float*    S1     = (float*   )take((size_t)NN * HIDD * 4);   // 102.4 MB (reused for S2)
    float*    h      = (float*   )take((size_t)NN * HIDD * 4);   // 102.4 MB
    ushort_t* W1tHi  = (ushort_t*)take((size_t)IND * HIDD * 2);
    ushort_t* W1tLo  = (ushort_t*)take((size_t)IND * HIDD * 2);
    ushort_t* W2tHi  = (ushort_t*)take((size_t)HIDD * OUTD * 2);
    ushort_t* W2tLo  = (ushort_t*)take((size_t)HIDD * OUTD * 2);
    int*      rowptr = (int*     )take((size_t)(NN + 1) * 4);
    int*      cnt    = (int*     )take((size_t)NN * 4);
    int*      cursor = (int*     )take((size_t)NN * 4);
    int*      part   = (int*     )take(512 * 4);
    int2*     esw    = (int2*    )take((size_t)NE * 8);          // 25.6 MB
    float*    S2     = S1;                                       // alias: S1 dead after spmm1
    (void)in_sizes; (void)n_in; (void)out_size; (void)ws_size;

    const int NB = (NN + 255) / 256;          // 391
    const int MB = (NN + 127) / 128;          // 782

    hipMemsetAsync(cnt, 0, (size_t)NN * 4, stream);
    splitw_k<<<(IND * HIDD + 255) / 256, 256, 0, stream>>>(W1, W1tHi, W1tLo, IND, HIDD);
    splitw_k<<<(HIDD * OUTD + 255) / 256, 256, 0, stream>>>(W2, W2tHi, W2tLo, HIDD, OUTD);

    hist_k<<<(NE + 255) / 256, 256, 0, stream>>>(dst, cnt);
    scan1_k<<<NB, 256, 0, stream>>>(cnt, rowptr, part, NN);
    scan2_k<<<1, 512, 0, stream>>>(part, NB);
    scan3_k<<<NB, 256, 0, stream>>>(rowptr, part, NN, NE);
    hipMemcpyAsync(cursor, rowptr, (size_t)NN * 4, hipMemcpyDeviceToDevice, stream);
    fill_k<<<(NE + 255) / 256, 256, 0, stream>>>(src, dst, ew, cursor, esw);

    // layer 1: S1 = x @ W1 (fp32-accurate split GEMM), h = relu(A_sp @ S1)
    gemm_split_k<<<dim3(MB, HIDD / 64), 256, 0, stream>>>(x, W1tHi, W1tLo, S1, NN, HIDD, IND);
    spmm_relu_k<<<NN / 4, 256, 0, stream>>>(rowptr, esw, S1, h);
    // layer 2: S2 = h @ W2, out = softmax(A_sp @ S2)
    gemm_split_k<<<dim3(MB, OUTD / 64), 256, 0, stream>>>(h, W2tHi, W2tLo, S2, NN, OUTD, HIDD);
    spmm_softmax_k<<<NN / 4, 256, 0, stream>>>(rowptr, esw, S2, out);
}

// Round 5
// 1366.314 us; speedup vs baseline: 1.2692x; 1.0018x over previous
//
#include <hip/hip_runtime.h>
#include <hip/hip_bf16.h>

typedef __attribute__((ext_vector_type(8))) short bf16x8;   // 8 bf16 = 4 VGPRs (MFMA A/B frag)
typedef __attribute__((ext_vector_type(4))) float f32x4;    // MFMA C/D frag
typedef unsigned short ushort_t;

#define NN   100000
#define NE   3200000
#define IND  512
#define HIDD 256
#define OUTD 64

// bf16 helpers (RTNE, manual bit math — no NaN inputs in this problem)
__device__ __forceinline__ ushort_t f2bf(float a) {
    unsigned u = __float_as_uint(a);
    unsigned r = (u + 0x7FFFu + ((u >> 16) & 1u)) >> 16;
    return (ushort_t)r;
}
__device__ __forceinline__ float bf2f(ushort_t b) {
    return __uint_as_float(((unsigned)b) << 16);
}

union U8 { ushort_t us[8]; uint4 v; };

// ------------------------------------------------- weight transpose + hi/lo split
// in: fp32 [R,C] row-major -> out hi/lo: bf16 [C,R] (i.e. B^T with contiguous K)
__global__ void splitw_k(const float* __restrict__ in, ushort_t* __restrict__ thi,
                         ushort_t* __restrict__ tlo, int R, int C) {
    int i = blockIdx.x * 256 + threadIdx.x;
    if (i < R * C) {
        int r = i / C, c = i % C;
        float a = in[i];
        ushort_t h = f2bf(a);
        thi[(size_t)c * R + r] = h;
        tlo[(size_t)c * R + r] = f2bf(a - bf2f(h));
    }
}

// ------------------------------------------------- split-bf16 GEMM (fp32-accurate)
// C[M,N] = A[M,K] @ B[K,N]; A fp32 (split on the fly), Bt pre-split bf16 [N,K].
// BM=128, BN=64, BK=32; 256 threads = 4 waves; wave tile 32x64 as 2x4 mfma tiles.
__global__ __launch_bounds__(256) void gemm_split_k(
    const float* __restrict__ A, const ushort_t* __restrict__ BtHi,
    const ushort_t* __restrict__ BtLo, float* __restrict__ C,
    int M, int N, int K)
{
    // row stride 40 elems = 80 B = 20 banks -> only 2-way LDS aliasing (free)
    __shared__ __align__(16) ushort_t sAh[128][40];
    __shared__ __align__(16) ushort_t sAl[128][40];
    __shared__ __align__(16) ushort_t sBh[64][40];
    __shared__ __align__(16) ushort_t sBl[64][40];

    const int tid  = threadIdx.x;
    const int wave = tid >> 6;
    const int lane = tid & 63;
    const int quad = lane >> 4;
    const int l15  = lane & 15;
    const int m0   = blockIdx.x * 128;
    const int n0   = blockIdx.y * 64;

    f32x4 acc[2][4] = {};

    const int sr = tid >> 2;          // 0..63 staging row
    const int sc = (tid & 3) * 8;     // 0,8,16,24 staging col (k)

    for (int k0 = 0; k0 < K; k0 += 32) {
        // stage A: 128 rows x 32 k, fp32 -> hi/lo bf16, two sweeps of 64 rows
        #pragma unroll
        for (int it = 0; it < 2; ++it) {
            int rr = sr + it * 64;
            int gr = m0 + rr;
            float4 v0 = make_float4(0.f, 0.f, 0.f, 0.f);
            float4 v1 = v0;
            if (gr < M) {
                const float* p = A + (size_t)gr * K + k0 + sc;
                v0 = *(const float4*)p;
                v1 = *(const float4*)(p + 4);
            }
            float vv[8] = {v0.x, v0.y, v0.z, v0.w, v1.x, v1.y, v1.z, v1.w};
            U8 H, L;
            #pragma unroll
            for (int j = 0; j < 8; ++j) {
                ushort_t h = f2bf(vv[j]);
                H.us[j] = h;
                L.us[j] = f2bf(vv[j] - bf2f(h));
            }
            *(uint4*)&sAh[rr][sc] = H.v;
            *(uint4*)&sAl[rr][sc] = L.v;
        }
        // stage Bt (pre-split): 64 rows x 32 k
        *(uint4*)&sBh[sr][sc] = *(const uint4*)(BtHi + (size_t)(n0 + sr) * K + k0 + sc);
        *(uint4*)&sBl[sr][sc] = *(const uint4*)(BtLo + (size_t)(n0 + sr) * K + k0 + sc);
        __syncthreads();

        bf16x8 aH[2], aL[2], bH[4], bL[4];
        #pragma unroll
        for (int ms = 0; ms < 2; ++ms) {
            aH[ms] = *(const bf16x8*)&sAh[wave * 32 + ms * 16 + l15][quad * 8];
            aL[ms] = *(const bf16x8*)&sAl[wave * 32 + ms * 16 + l15][quad * 8];
        }
        #pragma unroll
        for (int ns = 0; ns < 4; ++ns) {
            bH[ns] = *(const bf16x8*)&sBh[ns * 16 + l15][quad * 8];
            bL[ns] = *(const bf16x8*)&sBl[ns * 16 + l15][quad * 8];
        }

        #pragma unroll
        for (int ms = 0; ms < 2; ++ms)
            #pragma unroll
            for (int ns = 0; ns < 4; ++ns) {
                acc[ms][ns] = __builtin_amdgcn_mfma_f32_16x16x32_bf16(
                    aH[ms], bH[ns], acc[ms][ns], 0, 0, 0);
                acc[ms][ns] = __builtin_amdgcn_mfma_f32_16x16x32_bf16(
                    aL[ms], bH[ns], acc[ms][ns], 0, 0, 0);
                acc[ms][ns] = __builtin_amdgcn_mfma_f32_16x16x32_bf16(
                    aH[ms], bL[ns], acc[ms][ns], 0, 0, 0);
            }
        __syncthreads();
    }

    // epilogue: C/D layout col=lane&15, row=quad*4+reg
    #pragma unroll
    for (int ms = 0; ms < 2; ++ms) {
        int rowbase = m0 + wave * 32 + ms * 16 + quad * 4;
        #pragma unroll
        for (int ns = 0; ns < 4; ++ns) {
            int col = n0 + ns * 16 + l15;
            #pragma unroll
            for (int r = 0; r < 4; ++r) {
                int row = rowbase + r;
                if (row < M) C[(size_t)row * N + col] = acc[ms][ns][r];
            }
        }
    }
}

// ---------------------------------------------------------------- CSR build
__global__ void hist_k(const int* __restrict__ dst, int* __restrict__ cnt) {
    int i = blockIdx.x * 256 + threadIdx.x;
    if (i < NE) atomicAdd(&cnt[dst[i]], 1);
}

__global__ __launch_bounds__(256) void scan1_k(const int* __restrict__ in,
                                               int* __restrict__ excl,
                                               int* __restrict__ part, int n) {
    __shared__ int s[256];
    int t = threadIdx.x;
    int i = blockIdx.x * 256 + t;
    int v = (i < n) ? in[i] : 0;
    s[t] = v;
    #pragma unroll
    for (int off = 1; off < 256; off <<= 1) {
        __syncthreads();
        int add = (t >= off) ? s[t - off] : 0;
        __syncthreads();
        s[t] += add;
    }
    __syncthreads();
    if (i < n) excl[i] = s[t] - v;
    if (t == 255) part[blockIdx.x] = s[255];
}

__global__ __launch_bounds__(512) void scan2_k(int* __restrict__ part, int nb) {
    __shared__ int s[512];
    int t = threadIdx.x;
    int v = (t < nb) ? part[t] : 0;
    s[t] = v;
    for (int off = 1; off < 512; off <<= 1) {
        __syncthreads();
        int add = (t >= off) ? s[t - off] : 0;
        __syncthreads();
        s[t] += add;
    }
    __syncthreads();
    if (t < nb) part[t] = s[t] - v;
}

__global__ void scan3_k(int* __restrict__ excl, const int* __restrict__ part,
                        int n, int total) {
    int i = blockIdx.x * 256 + threadIdx.x;
    if (i < n) excl[i] += part[blockIdx.x];
    if (i == 0) excl[n] = total;
}

__global__ void fill_k(const int* __restrict__ src, const int* __restrict__ dst,
                       const float* __restrict__ w, int* __restrict__ cursor,
                       int2* __restrict__ esw) {
    int i = blockIdx.x * 256 + threadIdx.x;
    if (i < NE) {
        int d = dst[i];
        int p = atomicAdd(&cursor[d], 1);
        esw[p] = make_int2(src[i], __float_as_int(w[i]));
    }
}

// ---------------------------------------------------------------- SpMM layer 1 (+ReLU)
// Feature-chunked: 4 sequential passes, each gathering a 64-float (256 B)
// slice of X -> per-pass working set 25.6 MB, L3-resident (kills the ~50%
// HBM miss rate seen at full-row gathers). One wave per node, lane = feature
// within chunk. Edge-sum order per feature identical to the verified kernel.
__global__ __launch_bounds__(256) void spmm_relu_chunk_k(
    const int* __restrict__ rowptr, const int2* __restrict__ esw,
    const float* __restrict__ X, float* __restrict__ Y, int c0)
{
    const int wave = threadIdx.x >> 6;
    const int lane = threadIdx.x & 63;
    const int node = blockIdx.x * 4 + wave;
    const int beg = rowptr[node], end = rowptr[node + 1];
    float acc = 0.f;
    const float* Xl = X + c0 + lane;
    #pragma unroll 8
    for (int e = beg; e < end; ++e) {
        int2 sw = esw[e];
        acc += __int_as_float(sw.y) * Xl[(size_t)sw.x * HIDD];
    }
    Y[(size_t)node * HIDD + c0 + lane] = fmaxf(acc, 0.f);
}

// ---------------------------------------------------------------- SpMM layer 2 + softmax
// one wave per dst node; lane = feature column (64). X table is 25.6 MB —
// already chunk-sized / L3-resident.
__global__ __launch_bounds__(256) void spmm_softmax_k(
    const int* __restrict__ rowptr, const int2* __restrict__ esw,
    const float* __restrict__ X, float* __restrict__ out)
{
    int node = blockIdx.x * 4 + (threadIdx.x >> 6);
    int lane = threadIdx.x & 63;
    int beg = rowptr[node], end = rowptr[node + 1];
    float acc = 0.f;
    #pragma unroll 4
    for (int e = beg; e < end; ++e) {
        int2 sw = esw[e];
        acc += __int_as_float(sw.y) * X[(size_t)sw.x * OUTD + lane];
    }
    // softmax over 64 lanes (degree-0 rows -> uniform 1/64, matches reference)
    float mx = acc;
    #pragma unroll
    for (int off = 32; off > 0; off >>= 1) mx = fmaxf(mx, __shfl_xor(mx, off));
    float ex = __expf(acc - mx);
    float sm = ex;
    #pragma unroll
    for (int off = 32; off > 0; off >>= 1) sm += __shfl_xor(sm, off);
    out[(size_t)node * OUTD + lane] = ex / sm;
}

// ---------------------------------------------------------------- launch
extern "C" void kernel_launch(void* const* d_in, const int* in_sizes, int n_in,
                              void* d_out, int out_size, void* d_ws, size_t ws_size,
                              hipStream_t stream) {
    const float* x  = (const float*)d_in[0];
    const int*   ei = (const int*)d_in[1];
    const float* ew = (const float*)d_in[2];
    const float* W1 = (const float*)d_in[3];
    const float* W2 = (const float*)d_in[4];
    float* out = (float*)d_out;
    const int* src = ei;        // edge_index row 0
    const int* dst = ei + NE;   // edge_index row 1

    char* ws = (char*)d_ws;
    size_t o = 0;
    auto take = [&](size_t bytes) -> void* {
        void* p = (void*)(ws + o);
        o += (bytes + 255) & ~(size_t)255;
        return p;
    };
    float*    S1     = (float*   )take((size_t)NN * HIDD * 4);   // 102.4 MB (reused for S2)
    float*    h      = (float*   )take((size_t)NN * HIDD * 4);   // 102.4 MB
    ushort_t* W1tHi  = (ushort_t*)take((size_t)IND * HIDD * 2);
    ushort_t* W1tLo  = (ushort_t*)take((size_t)IND * HIDD * 2);
    ushort_t* W2tHi  = (ushort_t*)take((size_t)HIDD * OUTD * 2);
    ushort_t* W2tLo  = (ushort_t*)take((size_t)HIDD * OUTD * 2);
    int*      rowptr = (int*     )take((size_t)(NN + 1) * 4);
    int*      cnt    = (int*     )take((size_t)NN * 4);
    int*      cursor = (int*     )take((size_t)NN * 4);
    int*      part   = (int*     )take(512 * 4);
    int2*     esw    = (int2*    )take((size_t)NE * 8);          // 25.6 MB
    float*    S2     = S1;                                       // alias: S1 dead after spmm1
    (void)in_sizes; (void)n_in; (void)out_size; (void)ws_size;

    const int NB = (NN + 255) / 256;          // 391
    const int MB = (NN + 127) / 128;          // 782

    hipMemsetAsync(cnt, 0, (size_t)NN * 4, stream);
    splitw_k<<<(IND * HIDD + 255) / 256, 256, 0, stream>>>(W1, W1tHi, W1tLo, IND, HIDD);
    splitw_k<<<(HIDD * OUTD + 255) / 256, 256, 0, stream>>>(W2, W2tHi, W2tLo, HIDD, OUTD);

    hist_k<<<(NE + 255) / 256, 256, 0, stream>>>(dst, cnt);
    scan1_k<<<NB, 256, 0, stream>>>(cnt, rowptr, part, NN);
    scan2_k<<<1, 512, 0, stream>>>(part, NB);
    scan3_k<<<NB, 256, 0, stream>>>(rowptr, part, NN, NE);
    hipMemcpyAsync(cursor, rowptr, (size_t)NN * 4, hipMemcpyDeviceToDevice, stream);
    fill_k<<<(NE + 255) / 256, 256, 0, stream>>>(src, dst, ew, cursor, esw);

    // layer 1: S1 = x @ W1 (fp32-accurate split GEMM)
    gemm_split_k<<<dim3(MB, HIDD / 64), 256, 0, stream>>>(x, W1tHi, W1tLo, S1, NN, HIDD, IND);
    // h = relu(A_sp @ S1), feature-chunked (4 passes, stream-serialized so
    // each pass's 25.6 MB gather slice stays L3-resident)
    for (int c0 = 0; c0 < HIDD; c0 += 64)
        spmm_relu_chunk_k<<<NN / 4, 256, 0, stream>>>(rowptr, esw, S1, h, c0);
    // layer 2: S2 = h @ W2, out = softmax(A_sp @ S2)
    gemm_split_k<<<dim3(MB, OUTD / 64), 256, 0, stream>>>(h, W2tHi, W2tLo, S2, NN, OUTD, HIDD);
    spmm_softmax_k<<<NN / 4, 256, 0, stream>>>(rowptr, esw, S2, out);
}

// Round 6
// 1159.513 us; speedup vs baseline: 1.4955x; 1.1784x over previous
//
#include <hip/hip_runtime.h>
#include <hip/hip_bf16.h>

typedef __attribute__((ext_vector_type(8))) short bf16x8;   // 8 bf16 = 4 VGPRs (MFMA A/B frag)
typedef __attribute__((ext_vector_type(4))) float f32x4;    // MFMA C/D frag
typedef unsigned short ushort_t;

#define NN   100000
#define NE   3200000
#define IND  512
#define HIDD 256
#define OUTD 64

#define NBKT 98            // buckets of 1024 nodes: ceil(100000/1024)=98
#define P1E  2048          // edges per phase-1 block

// bf16 helpers (RTNE, manual bit math — no NaN inputs in this problem)
__device__ __forceinline__ ushort_t f2bf(float a) {
    unsigned u = __float_as_uint(a);
    unsigned r = (u + 0x7FFFu + ((u >> 16) & 1u)) >> 16;
    return (ushort_t)r;
}
__device__ __forceinline__ float bf2f(ushort_t b) {
    return __uint_as_float(((unsigned)b) << 16);
}

union U8 { ushort_t us[8]; uint4 v; };

// ------------------------------------------------- weight transpose + hi/lo split
__global__ void splitw_k(const float* __restrict__ in, ushort_t* __restrict__ thi,
                         ushort_t* __restrict__ tlo, int R, int C) {
    int i = blockIdx.x * 256 + threadIdx.x;
    if (i < R * C) {
        int r = i / C, c = i % C;
        float a = in[i];
        ushort_t h = f2bf(a);
        thi[(size_t)c * R + r] = h;
        tlo[(size_t)c * R + r] = f2bf(a - bf2f(h));
    }
}

// ------------------------------------------------- split-bf16 GEMM, single panel
// (kept for layer 2, N=64). C[M,N] = A[M,K] @ B; Bt pre-split bf16 [N,K].
__global__ __launch_bounds__(256) void gemm_split_k(
    const float* __restrict__ A, const ushort_t* __restrict__ BtHi,
    const ushort_t* __restrict__ BtLo, float* __restrict__ C,
    int M, int N, int K)
{
    __shared__ __align__(16) ushort_t sAh[128][40];
    __shared__ __align__(16) ushort_t sAl[128][40];
    __shared__ __align__(16) ushort_t sBh[64][40];
    __shared__ __align__(16) ushort_t sBl[64][40];

    const int tid  = threadIdx.x;
    const int wave = tid >> 6;
    const int lane = tid & 63;
    const int quad = lane >> 4;
    const int l15  = lane & 15;
    const int m0   = blockIdx.x * 128;
    const int n0   = blockIdx.y * 64;

    f32x4 acc[2][4] = {};
    const int sr = tid >> 2;
    const int sc = (tid & 3) * 8;

    for (int k0 = 0; k0 < K; k0 += 32) {
        #pragma unroll
        for (int it = 0; it < 2; ++it) {
            int rr = sr + it * 64;
            int gr = m0 + rr;
            float4 v0 = make_float4(0.f, 0.f, 0.f, 0.f);
            float4 v1 = v0;
            if (gr < M) {
                const float* p = A + (size_t)gr * K + k0 + sc;
                v0 = *(const float4*)p;
                v1 = *(const float4*)(p + 4);
            }
            float vv[8] = {v0.x, v0.y, v0.z, v0.w, v1.x, v1.y, v1.z, v1.w};
            U8 H, L;
            #pragma unroll
            for (int j = 0; j < 8; ++j) {
                ushort_t h = f2bf(vv[j]);
                H.us[j] = h;
                L.us[j] = f2bf(vv[j] - bf2f(h));
            }
            *(uint4*)&sAh[rr][sc] = H.v;
            *(uint4*)&sAl[rr][sc] = L.v;
        }
        *(uint4*)&sBh[sr][sc] = *(const uint4*)(BtHi + (size_t)(n0 + sr) * K + k0 + sc);
        *(uint4*)&sBl[sr][sc] = *(const uint4*)(BtLo + (size_t)(n0 + sr) * K + k0 + sc);
        __syncthreads();

        bf16x8 aH[2], aL[2], bH[4], bL[4];
        #pragma unroll
        for (int ms = 0; ms < 2; ++ms) {
            aH[ms] = *(const bf16x8*)&sAh[wave * 32 + ms * 16 + l15][quad * 8];
            aL[ms] = *(const bf16x8*)&sAl[wave * 32 + ms * 16 + l15][quad * 8];
        }
        #pragma unroll
        for (int ns = 0; ns < 4; ++ns) {
            bH[ns] = *(const bf16x8*)&sBh[ns * 16 + l15][quad * 8];
            bL[ns] = *(const bf16x8*)&sBl[ns * 16 + l15][quad * 8];
        }
        #pragma unroll
        for (int ms = 0; ms < 2; ++ms)
            #pragma unroll
            for (int ns = 0; ns < 4; ++ns) {
                acc[ms][ns] = __builtin_amdgcn_mfma_f32_16x16x32_bf16(aH[ms], bH[ns], acc[ms][ns], 0, 0, 0);
                acc[ms][ns] = __builtin_amdgcn_mfma_f32_16x16x32_bf16(aL[ms], bH[ns], acc[ms][ns], 0, 0, 0);
                acc[ms][ns] = __builtin_amdgcn_mfma_f32_16x16x32_bf16(aH[ms], bL[ns], acc[ms][ns], 0, 0, 0);
            }
        __syncthreads();
    }

    #pragma unroll
    for (int ms = 0; ms < 2; ++ms) {
        int rowbase = m0 + wave * 32 + ms * 16 + quad * 4;
        #pragma unroll
        for (int ns = 0; ns < 4; ++ns) {
            int col = n0 + ns * 16 + l15;
            #pragma unroll
            for (int r = 0; r < 4; ++r) {
                int row = rowbase + r;
                if (row < M) C[(size_t)row * N + col] = acc[ms][ns][r];
            }
        }
    }
}

// ------------------------------------------------- split-bf16 GEMM, 4-panel
// Layer 1 only: M=NN, N=256, K=512. Stages A hi/lo ONCE per k0 and computes
// all four 64-col panels (A HBM traffic 820->205 MB; split VALU amortized 4x).
__global__ __launch_bounds__(256) void gemm_split4_k(
    const float* __restrict__ A, const ushort_t* __restrict__ BtHi,
    const ushort_t* __restrict__ BtLo, float* __restrict__ C)
{
    const int M = NN, N = HIDD, K = IND;
    __shared__ __align__(16) ushort_t sAh[128][40];
    __shared__ __align__(16) ushort_t sAl[128][40];
    __shared__ __align__(16) ushort_t sBh[256][40];
    __shared__ __align__(16) ushort_t sBl[256][40];

    const int tid  = threadIdx.x;
    const int wave = tid >> 6;
    const int lane = tid & 63;
    const int quad = lane >> 4;
    const int l15  = lane & 15;
    const int m0   = blockIdx.x * 128;

    f32x4 acc[2][16] = {};
    const int sr = tid >> 2;
    const int sc = (tid & 3) * 8;

    for (int k0 = 0; k0 < K; k0 += 32) {
        // stage A: 128 rows x 32 k, fp32 -> hi/lo
        #pragma unroll
        for (int it = 0; it < 2; ++it) {
            int rr = sr + it * 64;
            int gr = m0 + rr;
            float4 v0 = make_float4(0.f, 0.f, 0.f, 0.f);
            float4 v1 = v0;
            if (gr < M) {
                const float* p = A + (size_t)gr * K + k0 + sc;
                v0 = *(const float4*)p;
                v1 = *(const float4*)(p + 4);
            }
            float vv[8] = {v0.x, v0.y, v0.z, v0.w, v1.x, v1.y, v1.z, v1.w};
            U8 H, L;
            #pragma unroll
            for (int j = 0; j < 8; ++j) {
                ushort_t h = f2bf(vv[j]);
                H.us[j] = h;
                L.us[j] = f2bf(vv[j] - bf2f(h));
            }
            *(uint4*)&sAh[rr][sc] = H.v;
            *(uint4*)&sAl[rr][sc] = L.v;
        }
        // stage Bt: all 256 rows x 32 k (4 sweeps), pre-split
        #pragma unroll
        for (int it = 0; it < 4; ++it) {
            int rr = sr + it * 64;
            *(uint4*)&sBh[rr][sc] = *(const uint4*)(BtHi + (size_t)rr * K + k0 + sc);
            *(uint4*)&sBl[rr][sc] = *(const uint4*)(BtLo + (size_t)rr * K + k0 + sc);
        }
        __syncthreads();

        bf16x8 aH[2], aL[2];
        #pragma unroll
        for (int ms = 0; ms < 2; ++ms) {
            aH[ms] = *(const bf16x8*)&sAh[wave * 32 + ms * 16 + l15][quad * 8];
            aL[ms] = *(const bf16x8*)&sAl[wave * 32 + ms * 16 + l15][quad * 8];
        }
        #pragma unroll
        for (int p = 0; p < 4; ++p) {
            bf16x8 bH[4], bL[4];
            #pragma unroll
            for (int ns = 0; ns < 4; ++ns) {
                bH[ns] = *(const bf16x8*)&sBh[p * 64 + ns * 16 + l15][quad * 8];
                bL[ns] = *(const bf16x8*)&sBl[p * 64 + ns * 16 + l15][quad * 8];
            }
            #pragma unroll
            for (int ms = 0; ms < 2; ++ms)
                #pragma unroll
                for (int ns = 0; ns < 4; ++ns) {
                    int j = p * 4 + ns;
                    acc[ms][j] = __builtin_amdgcn_mfma_f32_16x16x32_bf16(aH[ms], bH[ns], acc[ms][j], 0, 0, 0);
                    acc[ms][j] = __builtin_amdgcn_mfma_f32_16x16x32_bf16(aL[ms], bH[ns], acc[ms][j], 0, 0, 0);
                    acc[ms][j] = __builtin_amdgcn_mfma_f32_16x16x32_bf16(aH[ms], bL[ns], acc[ms][j], 0, 0, 0);
                }
        }
        __syncthreads();
    }

    #pragma unroll
    for (int ms = 0; ms < 2; ++ms) {
        int rowbase = m0 + wave * 32 + ms * 16 + quad * 4;
        #pragma unroll
        for (int j = 0; j < 16; ++j) {
            int col = (j >> 2) * 64 + (j & 3) * 16 + l15;
            #pragma unroll
            for (int r = 0; r < 4; ++r) {
                int row = rowbase + r;
                if (row < M) C[(size_t)row * N + col] = acc[ms][j][r];
            }
        }
    }
}

// ---------------------------------------------------------------- CSR build (binned)
// bucket = dst >> 10 (1024 nodes per bucket, 98 buckets)

__global__ __launch_bounds__(256) void bhist_k(const int* __restrict__ dst,
                                               int* __restrict__ bucketHist) {
    __shared__ int h[NBKT];
    int t = threadIdx.x;
    if (t < NBKT) h[t] = 0;
    __syncthreads();
    #pragma unroll
    for (int j = 0; j < 4; ++j) {
        int e = blockIdx.x * 1024 + t + j * 256;
        if (e < NE) atomicAdd(&h[dst[e] >> 10], 1);
    }
    __syncthreads();
    if (t < NBKT && h[t]) atomicAdd(&bucketHist[t], h[t]);
}

__global__ __launch_bounds__(128) void bscan_k(const int* __restrict__ bucketHist,
                                               int* __restrict__ bucketStart,
                                               int* __restrict__ bucketCursor) {
    __shared__ int s[128];
    int t = threadIdx.x;
    int v = (t < NBKT) ? bucketHist[t] : 0;
    s[t] = v;
    for (int off = 1; off < 128; off <<= 1) {
        __syncthreads();
        int a = (t >= off) ? s[t - off] : 0;
        __syncthreads();
        s[t] += a;
    }
    __syncthreads();
    if (t < NBKT) { bucketStart[t] = s[t] - v; bucketCursor[t] = s[t] - v; }
    if (t == NBKT - 1) bucketStart[NBKT] = s[t];
}

// phase 1: bin edges into bucket regions. Entry: (src | dstLow<<17, w_bits).
// LDS reorder -> coalesced run flush (runs avg 21 edges per bucket per block).
__global__ __launch_bounds__(256) void phase1_k(
    const int* __restrict__ src, const int* __restrict__ dst,
    const float* __restrict__ w, int* __restrict__ bucketCursor,
    int2* __restrict__ binned)
{
    __shared__ int2 raw[P1E];
    __shared__ int2 ord[P1E];
    __shared__ ushort_t rbkt[P1E], obkt[P1E];
    __shared__ int hist[128], excl[128], cursor[128], gbase[128], stmp[128];

    int t = threadIdx.x;
    if (t < 128) hist[t] = 0;
    __syncthreads();

    int e0 = blockIdx.x * P1E;
    #pragma unroll
    for (int j = 0; j < P1E / 256; ++j) {
        int li = t + j * 256;
        int e = e0 + li;
        if (e < NE) {
            int d = dst[e];
            int b = d >> 10;
            raw[li] = make_int2(src[e] | ((d & 1023) << 17), __float_as_int(w[e]));
            rbkt[li] = (ushort_t)b;
            atomicAdd(&hist[b], 1);
        } else rbkt[li] = 0xFFFFu;
    }
    __syncthreads();
    // exclusive scan of hist[0..127]
    int v = (t < 128) ? hist[t] : 0;
    if (t < 128) stmp[t] = v;
    for (int off = 1; off < 128; off <<= 1) {
        __syncthreads();
        int a = (t < 128 && t >= off) ? stmp[t - off] : 0;
        __syncthreads();
        if (t < 128) stmp[t] += a;
    }
    __syncthreads();
    if (t < 128) { excl[t] = stmp[t] - v; cursor[t] = stmp[t] - v; }
    if (t < NBKT) gbase[t] = atomicAdd(&bucketCursor[t], hist[t]);
    __syncthreads();
    #pragma unroll
    for (int j = 0; j < P1E / 256; ++j) {
        int li = t + j * 256;
        ushort_t b = rbkt[li];
        if (b != 0xFFFFu) {
            int p = atomicAdd(&cursor[b], 1);
            ord[p] = raw[li];
            obkt[p] = b;
        }
    }
    __syncthreads();
    int tot = excl[NBKT - 1] + hist[NBKT - 1];
    #pragma unroll
    for (int j = 0; j < P1E / 256; ++j) {
        int li = t + j * 256;
        if (li < tot) {
            int b = obkt[li];
            binned[(size_t)gbase[b] + (li - excl[b])] = ord[li];
        }
    }
}

// phase 2: one block per bucket. Per-node counts -> rowptr; scatter edges to
// final CSR slots (writes confined to a ~262 KB L2-hot window -> full lines).
__global__ __launch_bounds__(256) void phase2_k(
    const int* __restrict__ bucketStart, const int2* __restrict__ binned,
    int* __restrict__ rowptr, int2* __restrict__ esw)
{
    __shared__ int cnt[1024], ex[1024], cur[1024], wsum[256];
    int t = threadIdx.x, blk = blockIdx.x;
    int gb = bucketStart[blk], ge = bucketStart[blk + 1];
    #pragma unroll
    for (int j = 0; j < 4; ++j) cnt[t + j * 256] = 0;
    __syncthreads();
    for (int e = gb + t; e < ge; e += 256)
        atomicAdd(&cnt[(binned[e].x >> 17) & 1023], 1);
    __syncthreads();
    // scan 1024: 4 serial per thread + block scan of partials
    int b4 = t * 4;
    int l0 = cnt[b4], l1 = cnt[b4 + 1], l2 = cnt[b4 + 2], l3 = cnt[b4 + 3];
    int ls = l0 + l1 + l2 + l3;
    wsum[t] = ls;
    for (int off = 1; off < 256; off <<= 1) {
        __syncthreads();
        int a = (t >= off) ? wsum[t - off] : 0;
        __syncthreads();
        wsum[t] += a;
    }
    __syncthreads();
    int be = wsum[t] - ls;
    ex[b4] = be;            cur[b4] = be;
    ex[b4 + 1] = be + l0;     cur[b4 + 1] = be + l0;
    ex[b4 + 2] = be + l0 + l1;  cur[b4 + 2] = be + l0 + l1;
    ex[b4 + 3] = be + l0 + l1 + l2; cur[b4 + 3] = be + l0 + l1 + l2;
    __syncthreads();
    int n0 = blk << 10;
    #pragma unroll
    for (int j = 0; j < 4; ++j) {
        int i = b4 + j;
        if (n0 + i < NN) rowptr[n0 + i] = gb + ex[i];
    }
    if (blk == NBKT - 1 && t == 0) rowptr[NN] = NE;
    for (int e = gb + t; e < ge; e += 256) {
        int2 en = binned[e];
        int d = (en.x >> 17) & 1023;
        int p = atomicAdd(&cur[d], 1);
        esw[(size_t)gb + p] = make_int2(en.x & 0x1FFFF, en.y);
    }
}

// ---------------------------------------------------------------- SpMM layer 1 (+ReLU)
__global__ __launch_bounds__(256) void spmm_relu_chunk_k(
    const int* __restrict__ rowptr, const int2* __restrict__ esw,
    const float* __restrict__ X, float* __restrict__ Y, int c0)
{
    const int wave = threadIdx.x >> 6;
    const int lane = threadIdx.x & 63;
    const int node = blockIdx.x * 4 + wave;
    const int beg = rowptr[node], end = rowptr[node + 1];
    float acc = 0.f;
    const float* Xl = X + c0 + lane;
    #pragma unroll 8
    for (int e = beg; e < end; ++e) {
        int2 sw = esw[e];
        acc += __int_as_float(sw.y) * Xl[(size_t)sw.x * HIDD];
    }
    Y[(size_t)node * HIDD + c0 + lane] = fmaxf(acc, 0.f);
}

// ---------------------------------------------------------------- SpMM layer 2 + softmax
__global__ __launch_bounds__(256) void spmm_softmax_k(
    const int* __restrict__ rowptr, const int2* __restrict__ esw,
    const float* __restrict__ X, float* __restrict__ out)
{
    int node = blockIdx.x * 4 + (threadIdx.x >> 6);
    int lane = threadIdx.x & 63;
    int beg = rowptr[node], end = rowptr[node + 1];
    float acc = 0.f;
    #pragma unroll 4
    for (int e = beg; e < end; ++e) {
        int2 sw = esw[e];
        acc += __int_as_float(sw.y) * X[(size_t)sw.x * OUTD + lane];
    }
    float mx = acc;
    #pragma unroll
    for (int off = 32; off > 0; off >>= 1) mx = fmaxf(mx, __shfl_xor(mx, off));
    float ex = __expf(acc - mx);
    float sm = ex;
    #pragma unroll
    for (int off = 32; off > 0; off >>= 1) sm += __shfl_xor(sm, off);
    out[(size_t)node * OUTD + lane] = ex / sm;
}

// ---------------------------------------------------------------- launch
extern "C" void kernel_launch(void* const* d_in, const int* in_sizes, int n_in,
                              void* d_out, int out_size, void* d_ws, size_t ws_size,
                              hipStream_t stream) {
    const float* x  = (const float*)d_in[0];
    const int*   ei = (const int*)d_in[1];
    const float* ew = (const float*)d_in[2];
    const float* W1 = (const float*)d_in[3];
    const float* W2 = (const float*)d_in[4];
    float* out = (float*)d_out;
    const int* src = ei;        // edge_index row 0
    const int* dst = ei + NE;   // edge_index row 1

    char* ws = (char*)d_ws;
    size_t o = 0;
    auto take = [&](size_t bytes) -> void* {
        void* p = (void*)(ws + o);
        o += (bytes + 255) & ~(size_t)255;
        return p;
    };
    float*    S1      = (float*   )take((size_t)NN * HIDD * 4);   // 102.4 MB (reused for S2)
    float*    h       = (float*   )take((size_t)NN * HIDD * 4);   // 102.4 MB (binned aliases it)
    ushort_t* W1tHi   = (ushort_t*)take((size_t)IND * HIDD * 2);
    ushort_t* W1tLo   = (ushort_t*)take((size_t)IND * HIDD * 2);
    ushort_t* W2tHi   = (ushort_t*)take((size_t)HIDD * OUTD * 2);
    ushort_t* W2tLo   = (ushort_t*)take((size_t)HIDD * OUTD * 2);
    int*      rowptr  = (int*     )take((size_t)(NN + 1) * 4);
    int*      bHist   = (int*     )take(NBKT * 4);
    int*      bStart  = (int*     )take((NBKT + 1) * 4);
    int*      bCursor = (int*     )take(NBKT * 4);
    int2*     esw     = (int2*    )take((size_t)NE * 8);          // 25.6 MB
    int2*     binned  = (int2*)h;                                 // alias: h written later
    float*    S2      = S1;                                       // alias: S1 dead after spmm1
    (void)in_sizes; (void)n_in; (void)out_size; (void)ws_size;

    const int MB = (NN + 127) / 128;          // 782

    hipMemsetAsync(bHist, 0, NBKT * 4, stream);
    splitw_k<<<(IND * HIDD + 255) / 256, 256, 0, stream>>>(W1, W1tHi, W1tLo, IND, HIDD);
    splitw_k<<<(HIDD * OUTD + 255) / 256, 256, 0, stream>>>(W2, W2tHi, W2tLo, HIDD, OUTD);

    // CSR build: bucket hist -> scan -> bin -> per-bucket node sort
    bhist_k<<<(NE + 1023) / 1024, 256, 0, stream>>>(dst, bHist);
    bscan_k<<<1, 128, 0, stream>>>(bHist, bStart, bCursor);
    phase1_k<<<(NE + P1E - 1) / P1E, 256, 0, stream>>>(src, dst, ew, bCursor, binned);
    phase2_k<<<NBKT, 256, 0, stream>>>(bStart, binned, rowptr, esw);

    // layer 1: S1 = x @ W1 (fp32-accurate split GEMM, 4-panel A-reuse)
    gemm_split4_k<<<MB, 256, 0, stream>>>(x, W1tHi, W1tLo, S1);
    // h = relu(A_sp @ S1), feature-chunked
    for (int c0 = 0; c0 < HIDD; c0 += 64)
        spmm_relu_chunk_k<<<NN / 4, 256, 0, stream>>>(rowptr, esw, S1, h, c0);
    // layer 2: S2 = h @ W2, out = softmax(A_sp @ S2)
    gemm_split_k<<<dim3(MB, OUTD / 64), 256, 0, stream>>>(h, W2tHi, W2tLo, S2, NN, OUTD, HIDD);
    spmm_softmax_k<<<NN / 4, 256, 0, stream>>>(rowptr, esw, S2, out);
}

// Round 7
// 1065.891 us; speedup vs baseline: 1.6269x; 1.0878x over previous
//
#include <hip/hip_runtime.h>
#include <hip/hip_bf16.h>

typedef __attribute__((ext_vector_type(8))) short bf16x8;   // 8 bf16 = 4 VGPRs (MFMA A/B frag)
typedef __attribute__((ext_vector_type(4))) float f32x4;    // MFMA C/D frag
typedef __attribute__((ext_vector_type(4))) _Float16 f16x4; // 8 B gather unit
typedef unsigned short ushort_t;

#define NN   100000
#define NE   3200000
#define IND  512
#define HIDD 256
#define OUTD 64

#define NBKT 98            // buckets of 1024 nodes: ceil(100000/1024)=98
#define P1E  2048          // edges per phase-1 block

// bf16 helpers (RTNE, manual bit math — no NaN inputs in this problem)
__device__ __forceinline__ ushort_t f2bf(float a) {
    unsigned u = __float_as_uint(a);
    unsigned r = (u + 0x7FFFu + ((u >> 16) & 1u)) >> 16;
    return (ushort_t)r;
}
__device__ __forceinline__ float bf2f(ushort_t b) {
    return __uint_as_float(((unsigned)b) << 16);
}

union U8 { ushort_t us[8]; uint4 v; };

// ------------------------------------------------- weight transpose + hi/lo split
__global__ void splitw_k(const float* __restrict__ in, ushort_t* __restrict__ thi,
                         ushort_t* __restrict__ tlo, int R, int C) {
    int i = blockIdx.x * 256 + threadIdx.x;
    if (i < R * C) {
        int r = i / C, c = i % C;
        float a = in[i];
        ushort_t h = f2bf(a);
        thi[(size_t)c * R + r] = h;
        tlo[(size_t)c * R + r] = f2bf(a - bf2f(h));
    }
}

// ------------------------------------------------- split-bf16 GEMM, single panel
// layer 2 only (N=64): C = A @ B, fp32-accurate, OUTPUT fp16 (gather table).
__global__ __launch_bounds__(256) void gemm_split_k(
    const float* __restrict__ A, const ushort_t* __restrict__ BtHi,
    const ushort_t* __restrict__ BtLo, _Float16* __restrict__ C,
    int M, int N, int K)
{
    __shared__ __align__(16) ushort_t sAh[128][40];
    __shared__ __align__(16) ushort_t sAl[128][40];
    __shared__ __align__(16) ushort_t sBh[64][40];
    __shared__ __align__(16) ushort_t sBl[64][40];

    const int tid  = threadIdx.x;
    const int wave = tid >> 6;
    const int lane = tid & 63;
    const int quad = lane >> 4;
    const int l15  = lane & 15;
    const int m0   = blockIdx.x * 128;
    const int n0   = blockIdx.y * 64;

    f32x4 acc[2][4] = {};
    const int sr = tid >> 2;
    const int sc = (tid & 3) * 8;

    for (int k0 = 0; k0 < K; k0 += 32) {
        #pragma unroll
        for (int it = 0; it < 2; ++it) {
            int rr = sr + it * 64;
            int gr = m0 + rr;
            float4 v0 = make_float4(0.f, 0.f, 0.f, 0.f);
            float4 v1 = v0;
            if (gr < M) {
                const float* p = A + (size_t)gr * K + k0 + sc;
                v0 = *(const float4*)p;
                v1 = *(const float4*)(p + 4);
            }
            float vv[8] = {v0.x, v0.y, v0.z, v0.w, v1.x, v1.y, v1.z, v1.w};
            U8 H, L;
            #pragma unroll
            for (int j = 0; j < 8; ++j) {
                ushort_t h = f2bf(vv[j]);
                H.us[j] = h;
                L.us[j] = f2bf(vv[j] - bf2f(h));
            }
            *(uint4*)&sAh[rr][sc] = H.v;
            *(uint4*)&sAl[rr][sc] = L.v;
        }
        *(uint4*)&sBh[sr][sc] = *(const uint4*)(BtHi + (size_t)(n0 + sr) * K + k0 + sc);
        *(uint4*)&sBl[sr][sc] = *(const uint4*)(BtLo + (size_t)(n0 + sr) * K + k0 + sc);
        __syncthreads();

        bf16x8 aH[2], aL[2], bH[4], bL[4];
        #pragma unroll
        for (int ms = 0; ms < 2; ++ms) {
            aH[ms] = *(const bf16x8*)&sAh[wave * 32 + ms * 16 + l15][quad * 8];
            aL[ms] = *(const bf16x8*)&sAl[wave * 32 + ms * 16 + l15][quad * 8];
        }
        #pragma unroll
        for (int ns = 0; ns < 4; ++ns) {
            bH[ns] = *(const bf16x8*)&sBh[ns * 16 + l15][quad * 8];
            bL[ns] = *(const bf16x8*)&sBl[ns * 16 + l15][quad * 8];
        }
        #pragma unroll
        for (int ms = 0; ms < 2; ++ms)
            #pragma unroll
            for (int ns = 0; ns < 4; ++ns) {
                acc[ms][ns] = __builtin_amdgcn_mfma_f32_16x16x32_bf16(aH[ms], bH[ns], acc[ms][ns], 0, 0, 0);
                acc[ms][ns] = __builtin_amdgcn_mfma_f32_16x16x32_bf16(aL[ms], bH[ns], acc[ms][ns], 0, 0, 0);
                acc[ms][ns] = __builtin_amdgcn_mfma_f32_16x16x32_bf16(aH[ms], bL[ns], acc[ms][ns], 0, 0, 0);
            }
        __syncthreads();
    }

    #pragma unroll
    for (int ms = 0; ms < 2; ++ms) {
        int rowbase = m0 + wave * 32 + ms * 16 + quad * 4;
        #pragma unroll
        for (int ns = 0; ns < 4; ++ns) {
            int col = n0 + ns * 16 + l15;
            #pragma unroll
            for (int r = 0; r < 4; ++r) {
                int row = rowbase + r;
                if (row < M) C[(size_t)row * N + col] = (_Float16)acc[ms][ns][r];
            }
        }
    }
}

// ------------------------------------------------- split-bf16 GEMM, 4-panel
// layer 1: stages A hi/lo once per k0, computes all four 64-col panels.
// OUTPUT fp16 (S1 is only consumed as the SpMM1 gather table).
__global__ __launch_bounds__(256) void gemm_split4_k(
    const float* __restrict__ A, const ushort_t* __restrict__ BtHi,
    const ushort_t* __restrict__ BtLo, _Float16* __restrict__ C)
{
    const int M = NN, N = HIDD, K = IND;
    __shared__ __align__(16) ushort_t sAh[128][40];
    __shared__ __align__(16) ushort_t sAl[128][40];
    __shared__ __align__(16) ushort_t sBh[256][40];
    __shared__ __align__(16) ushort_t sBl[256][40];

    const int tid  = threadIdx.x;
    const int wave = tid >> 6;
    const int lane = tid & 63;
    const int quad = lane >> 4;
    const int l15  = lane & 15;
    const int m0   = blockIdx.x * 128;

    f32x4 acc[2][16] = {};
    const int sr = tid >> 2;
    const int sc = (tid & 3) * 8;

    for (int k0 = 0; k0 < K; k0 += 32) {
        #pragma unroll
        for (int it = 0; it < 2; ++it) {
            int rr = sr + it * 64;
            int gr = m0 + rr;
            float4 v0 = make_float4(0.f, 0.f, 0.f, 0.f);
            float4 v1 = v0;
            if (gr < M) {
                const float* p = A + (size_t)gr * K + k0 + sc;
                v0 = *(const float4*)p;
                v1 = *(const float4*)(p + 4);
            }
            float vv[8] = {v0.x, v0.y, v0.z, v0.w, v1.x, v1.y, v1.z, v1.w};
            U8 H, L;
            #pragma unroll
            for (int j = 0; j < 8; ++j) {
                ushort_t h = f2bf(vv[j]);
                H.us[j] = h;
                L.us[j] = f2bf(vv[j] - bf2f(h));
            }
            *(uint4*)&sAh[rr][sc] = H.v;
            *(uint4*)&sAl[rr][sc] = L.v;
        }
        #pragma unroll
        for (int it = 0; it < 4; ++it) {
            int rr = sr + it * 64;
            *(uint4*)&sBh[rr][sc] = *(const uint4*)(BtHi + (size_t)rr * K + k0 + sc);
            *(uint4*)&sBl[rr][sc] = *(const uint4*)(BtLo + (size_t)rr * K + k0 + sc);
        }
        __syncthreads();

        bf16x8 aH[2], aL[2];
        #pragma unroll
        for (int ms = 0; ms < 2; ++ms) {
            aH[ms] = *(const bf16x8*)&sAh[wave * 32 + ms * 16 + l15][quad * 8];
            aL[ms] = *(const bf16x8*)&sAl[wave * 32 + ms * 16 + l15][quad * 8];
        }
        #pragma unroll
        for (int p = 0; p < 4; ++p) {
            bf16x8 bH[4], bL[4];
            #pragma unroll
            for (int ns = 0; ns < 4; ++ns) {
                bH[ns] = *(const bf16x8*)&sBh[p * 64 + ns * 16 + l15][quad * 8];
                bL[ns] = *(const bf16x8*)&sBl[p * 64 + ns * 16 + l15][quad * 8];
            }
            #pragma unroll
            for (int ms = 0; ms < 2; ++ms)
                #pragma unroll
                for (int ns = 0; ns < 4; ++ns) {
                    int j = p * 4 + ns;
                    acc[ms][j] = __builtin_amdgcn_mfma_f32_16x16x32_bf16(aH[ms], bH[ns], acc[ms][j], 0, 0, 0);
                    acc[ms][j] = __builtin_amdgcn_mfma_f32_16x16x32_bf16(aL[ms], bH[ns], acc[ms][j], 0, 0, 0);
                    acc[ms][j] = __builtin_amdgcn_mfma_f32_16x16x32_bf16(aH[ms], bL[ns], acc[ms][j], 0, 0, 0);
                }
        }
        __syncthreads();
    }

    #pragma unroll
    for (int ms = 0; ms < 2; ++ms) {
        int rowbase = m0 + wave * 32 + ms * 16 + quad * 4;
        #pragma unroll
        for (int j = 0; j < 16; ++j) {
            int col = (j >> 2) * 64 + (j & 3) * 16 + l15;
            #pragma unroll
            for (int r = 0; r < 4; ++r) {
                int row = rowbase + r;
                if (row < M) C[(size_t)row * N + col] = (_Float16)acc[ms][j][r];
            }
        }
    }
}

// ---------------------------------------------------------------- CSR build (binned)
__global__ __launch_bounds__(256) void bhist_k(const int* __restrict__ dst,
                                               int* __restrict__ bucketHist) {
    __shared__ int h[NBKT];
    int t = threadIdx.x;
    if (t < NBKT) h[t] = 0;
    __syncthreads();
    #pragma unroll
    for (int j = 0; j < 4; ++j) {
        int e = blockIdx.x * 1024 + t + j * 256;
        if (e < NE) atomicAdd(&h[dst[e] >> 10], 1);
    }
    __syncthreads();
    if (t < NBKT && h[t]) atomicAdd(&bucketHist[t], h[t]);
}

__global__ __launch_bounds__(128) void bscan_k(const int* __restrict__ bucketHist,
                                               int* __restrict__ bucketStart,
                                               int* __restrict__ bucketCursor) {
    __shared__ int s[128];
    int t = threadIdx.x;
    int v = (t < NBKT) ? bucketHist[t] : 0;
    s[t] = v;
    for (int off = 1; off < 128; off <<= 1) {
        __syncthreads();
        int a = (t >= off) ? s[t - off] : 0;
        __syncthreads();
        s[t] += a;
    }
    __syncthreads();
    if (t < NBKT) { bucketStart[t] = s[t] - v; bucketCursor[t] = s[t] - v; }
    if (t == NBKT - 1) bucketStart[NBKT] = s[t];
}

__global__ __launch_bounds__(256) void phase1_k(
    const int* __restrict__ src, const int* __restrict__ dst,
    const float* __restrict__ w, int* __restrict__ bucketCursor,
    int2* __restrict__ binned)
{
    __shared__ int2 raw[P1E];
    __shared__ int2 ord[P1E];
    __shared__ ushort_t rbkt[P1E], obkt[P1E];
    __shared__ int hist[128], excl[128], cursor[128], gbase[128], stmp[128];

    int t = threadIdx.x;
    if (t < 128) hist[t] = 0;
    __syncthreads();

    int e0 = blockIdx.x * P1E;
    #pragma unroll
    for (int j = 0; j < P1E / 256; ++j) {
        int li = t + j * 256;
        int e = e0 + li;
        if (e < NE) {
            int d = dst[e];
            int b = d >> 10;
            raw[li] = make_int2(src[e] | ((d & 1023) << 17), __float_as_int(w[e]));
            rbkt[li] = (ushort_t)b;
            atomicAdd(&hist[b], 1);
        } else rbkt[li] = 0xFFFFu;
    }
    __syncthreads();
    int v = (t < 128) ? hist[t] : 0;
    if (t < 128) stmp[t] = v;
    for (int off = 1; off < 128; off <<= 1) {
        __syncthreads();
        int a = (t < 128 && t >= off) ? stmp[t - off] : 0;
        __syncthreads();
        if (t < 128) stmp[t] += a;
    }
    __syncthreads();
    if (t < 128) { excl[t] = stmp[t] - v; cursor[t] = stmp[t] - v; }
    if (t < NBKT) gbase[t] = atomicAdd(&bucketCursor[t], hist[t]);
    __syncthreads();
    #pragma unroll
    for (int j = 0; j < P1E / 256; ++j) {
        int li = t + j * 256;
        ushort_t b = rbkt[li];
        if (b != 0xFFFFu) {
            int p = atomicAdd(&cursor[b], 1);
            ord[p] = raw[li];
            obkt[p] = b;
        }
    }
    __syncthreads();
    int tot = excl[NBKT - 1] + hist[NBKT - 1];
    #pragma unroll
    for (int j = 0; j < P1E / 256; ++j) {
        int li = t + j * 256;
        if (li < tot) {
            int b = obkt[li];
            binned[(size_t)gbase[b] + (li - excl[b])] = ord[li];
        }
    }
}

__global__ __launch_bounds__(256) void phase2_k(
    const int* __restrict__ bucketStart, const int2* __restrict__ binned,
    int* __restrict__ rowptr, int2* __restrict__ esw)
{
    __shared__ int cnt[1024], ex[1024], cur[1024], wsum[256];
    int t = threadIdx.x, blk = blockIdx.x;
    int gb = bucketStart[blk], ge = bucketStart[blk + 1];
    #pragma unroll
    for (int j = 0; j < 4; ++j) cnt[t + j * 256] = 0;
    __syncthreads();
    for (int e = gb + t; e < ge; e += 256)
        atomicAdd(&cnt[(binned[e].x >> 17) & 1023], 1);
    __syncthreads();
    int b4 = t * 4;
    int l0 = cnt[b4], l1 = cnt[b4 + 1], l2 = cnt[b4 + 2], l3 = cnt[b4 + 3];
    int ls = l0 + l1 + l2 + l3;
    wsum[t] = ls;
    for (int off = 1; off < 256; off <<= 1) {
        __syncthreads();
        int a = (t >= off) ? wsum[t - off] : 0;
        __syncthreads();
        wsum[t] += a;
    }
    __syncthreads();
    int be = wsum[t] - ls;
    ex[b4] = be;            cur[b4] = be;
    ex[b4 + 1] = be + l0;     cur[b4 + 1] = be + l0;
    ex[b4 + 2] = be + l0 + l1;  cur[b4 + 2] = be + l0 + l1;
    ex[b4 + 3] = be + l0 + l1 + l2; cur[b4 + 3] = be + l0 + l1 + l2;
    __syncthreads();
    int n0 = blk << 10;
    #pragma unroll
    for (int j = 0; j < 4; ++j) {
        int i = b4 + j;
        if (n0 + i < NN) rowptr[n0 + i] = gb + ex[i];
    }
    if (blk == NBKT - 1 && t == 0) rowptr[NN] = NE;
    for (int e = gb + t; e < ge; e += 256) {
        int2 en = binned[e];
        int d = (en.x >> 17) & 1023;
        int p = atomicAdd(&cur[d], 1);
        esw[(size_t)gb + p] = make_int2(en.x & 0x1FFFF, en.y);
    }
}

// ---------------------------------------------------------------- SpMM layer 1 (+ReLU)
// one wave per node, lane owns 4 features (f16x4 8B load -> full 512B row per
// wave gather instr). fp16 gather table halves random-line traffic vs fp32.
__global__ __launch_bounds__(256) void spmm_relu_k(
    const int* __restrict__ rowptr, const int2* __restrict__ esw,
    const _Float16* __restrict__ X, float* __restrict__ Y)
{
    const int wave = threadIdx.x >> 6;
    const int lane = threadIdx.x & 63;
    const int node = blockIdx.x * 4 + wave;
    const int beg = rowptr[node], end = rowptr[node + 1];
    f32x4 acc = {0.f, 0.f, 0.f, 0.f};
    const _Float16* Xl = X + lane * 4;
    #pragma unroll 8
    for (int e = beg; e < end; ++e) {
        int2 sw = esw[e];
        float w = __int_as_float(sw.y);
        f16x4 v = *(const f16x4*)(Xl + (size_t)sw.x * HIDD);
        acc.x += (float)v[0] * w;
        acc.y += (float)v[1] * w;
        acc.z += (float)v[2] * w;
        acc.w += (float)v[3] * w;
    }
    f32x4 r;
    r.x = fmaxf(acc.x, 0.f);
    r.y = fmaxf(acc.y, 0.f);
    r.z = fmaxf(acc.z, 0.f);
    r.w = fmaxf(acc.w, 0.f);
    *(f32x4*)(Y + (size_t)node * HIDD + lane * 4) = r;
}

// ---------------------------------------------------------------- SpMM layer 2 + softmax
// one wave per node; lane = feature (64). fp16 gather table.
__global__ __launch_bounds__(256) void spmm_softmax_k(
    const int* __restrict__ rowptr, const int2* __restrict__ esw,
    const _Float16* __restrict__ X, float* __restrict__ out)
{
    int node = blockIdx.x * 4 + (threadIdx.x >> 6);
    int lane = threadIdx.x & 63;
    int beg = rowptr[node], end = rowptr[node + 1];
    float acc = 0.f;
    #pragma unroll 4
    for (int e = beg; e < end; ++e) {
        int2 sw = esw[e];
        acc += __int_as_float(sw.y) * (float)X[(size_t)sw.x * OUTD + lane];
    }
    float mx = acc;
    #pragma unroll
    for (int off = 32; off > 0; off >>= 1) mx = fmaxf(mx, __shfl_xor(mx, off));
    float ex = __expf(acc - mx);
    float sm = ex;
    #pragma unroll
    for (int off = 32; off > 0; off >>= 1) sm += __shfl_xor(sm, off);
    out[(size_t)node * OUTD + lane] = ex / sm;
}

// ---------------------------------------------------------------- launch
extern "C" void kernel_launch(void* const* d_in, const int* in_sizes, int n_in,
                              void* d_out, int out_size, void* d_ws, size_t ws_size,
                              hipStream_t stream) {
    const float* x  = (const float*)d_in[0];
    const int*   ei = (const int*)d_in[1];
    const float* ew = (const float*)d_in[2];
    const float* W1 = (const float*)d_in[3];
    const float* W2 = (const float*)d_in[4];
    float* out = (float*)d_out;
    const int* src = ei;        // edge_index row 0
    const int* dst = ei + NE;   // edge_index row 1

    char* ws = (char*)d_ws;
    size_t o = 0;
    auto take = [&](size_t bytes) -> void* {
        void* p = (void*)(ws + o);
        o += (bytes + 255) & ~(size_t)255;
        return p;
    };
    _Float16* S1      = (_Float16*)take((size_t)NN * HIDD * 2);   // 51.2 MB fp16 (reused for S2)
    float*    h       = (float*   )take((size_t)NN * HIDD * 4);   // 102.4 MB (binned aliases it)
    ushort_t* W1tHi   = (ushort_t*)take((size_t)IND * HIDD * 2);
    ushort_t* W1tLo   = (ushort_t*)take((size_t)IND * HIDD * 2);
    ushort_t* W2tHi   = (ushort_t*)take((size_t)HIDD * OUTD * 2);
    ushort_t* W2tLo   = (ushort_t*)take((size_t)HIDD * OUTD * 2);
    int*      rowptr  = (int*     )take((size_t)(NN + 1) * 4);
    int*      bHist   = (int*     )take(NBKT * 4);
    int*      bStart  = (int*     )take((NBKT + 1) * 4);
    int*      bCursor = (int*     )take(NBKT * 4);
    int2*     esw     = (int2*    )take((size_t)NE * 8);          // 25.6 MB
    int2*     binned  = (int2*)h;                                 // alias: h written later
    _Float16* S2      = S1;                                       // alias: S1 dead after spmm1
    (void)in_sizes; (void)n_in; (void)out_size; (void)ws_size;

    const int MB = (NN + 127) / 128;          // 782

    hipMemsetAsync(bHist, 0, NBKT * 4, stream);
    splitw_k<<<(IND * HIDD + 255) / 256, 256, 0, stream>>>(W1, W1tHi, W1tLo, IND, HIDD);
    splitw_k<<<(HIDD * OUTD + 255) / 256, 256, 0, stream>>>(W2, W2tHi, W2tLo, HIDD, OUTD);

    // CSR build: bucket hist -> scan -> bin -> per-bucket node sort
    bhist_k<<<(NE + 1023) / 1024, 256, 0, stream>>>(dst, bHist);
    bscan_k<<<1, 128, 0, stream>>>(bHist, bStart, bCursor);
    phase1_k<<<(NE + P1E - 1) / P1E, 256, 0, stream>>>(src, dst, ew, bCursor, binned);
    phase2_k<<<NBKT, 256, 0, stream>>>(bStart, binned, rowptr, esw);

    // layer 1: S1 = x @ W1 (fp32-accurate split GEMM, 4-panel A-reuse, fp16 out)
    gemm_split4_k<<<MB, 256, 0, stream>>>(x, W1tHi, W1tLo, S1);
    // h = relu(A_sp @ S1), single pass (fp16 gather, 8 B/lane)
    spmm_relu_k<<<NN / 4, 256, 0, stream>>>(rowptr, esw, S1, h);
    // layer 2: S2 = h @ W2 (fp16 out), out = softmax(A_sp @ S2)
    gemm_split_k<<<dim3(MB, OUTD / 64), 256, 0, stream>>>(h, W2tHi, W2tLo, S2, NN, OUTD, HIDD);
    spmm_softmax_k<<<NN / 4, 256, 0, stream>>>(rowptr, esw, S2, out);
}